// Round 7
// baseline (510.651 us; speedup 1.0000x reference)
//
#include <hip/hip_runtime.h>
#include <math.h>

typedef __bf16 bf16;
typedef __bf16 bf16x4 __attribute__((ext_vector_type(4)));
typedef __bf16 bf16x8 __attribute__((ext_vector_type(8)));
typedef float floatx4 __attribute__((ext_vector_type(4)));

#define MFMA16(a, b, c) __builtin_amdgcn_mfma_f32_16x16x32_bf16(a, b, c, 0, 0, 0)

#if __has_builtin(__builtin_amdgcn_exp2f)
#define EXP2F(x) __builtin_amdgcn_exp2f(x)
#else
#define EXP2F(x) exp2f(x)
#endif

constexpr int Bc = 4, SQc = 2048, SKVc = 2048, Hc = 16, Dc = 64;
// fold 1/sqrt(D) * log2(e) into qh so softmax is exp2 with no extra mul
#define QSCALE 0.18033688011112042f

// ---------------------------------------------------------------------------
// Prepass: fp32 -> bf16 convert (1024 elems per block)
// ---------------------------------------------------------------------------
__global__ void cvt_bf16(const float* __restrict__ in, bf16* __restrict__ out) {
  const size_t i = ((size_t)blockIdx.x * 256 + threadIdx.x) * 4;
  const float4 v = *(const float4*)&in[i];
  bf16x4 o = {(bf16)v.x, (bf16)v.y, (bf16)v.z, (bf16)v.w};
  *(bf16x4*)&out[i] = o;
}

// ---------------------------------------------------------------------------
// Prepass: W [K][N] fp32 -> WT [N][K] bf16. grid (N/64, K/64), 256 thr.
// ---------------------------------------------------------------------------
__global__ void transpose_cvt(const float* __restrict__ in, bf16* __restrict__ out,
                              int K, int N) {
  __shared__ bf16 T[64][72];
  const int tid = threadIdx.x;
  const int n0 = blockIdx.x * 64, k0 = blockIdx.y * 64;
  const int tr = tid >> 4, tc4 = (tid & 15) * 4;
#pragma unroll
  for (int i = 0; i < 4; i++) {
    const int k = tr + 16 * i;
    const float4 v = *(const float4*)&in[(size_t)(k0 + k) * N + n0 + tc4];
    T[tc4 + 0][k] = (bf16)v.x;
    T[tc4 + 1][k] = (bf16)v.y;
    T[tc4 + 2][k] = (bf16)v.z;
    T[tc4 + 3][k] = (bf16)v.w;
  }
  __syncthreads();
  const int nr = tid >> 2, kc = (tid & 3) * 8;
#pragma unroll
  for (int hf = 0; hf < 2; hf++)
    *(bf16x8*)&out[(size_t)(n0 + nr) * K + k0 + kc + 32 * hf] =
        *(const bf16x8*)&T[nr][kc + 32 * hf];
}

// ---------------------------------------------------------------------------
// 128x128-tile, BK=32, DOUBLE-BUFFERED register-prefetch K-loop.
// Per iter: barrier -> ds_read frags(buf cur) -> issue global loads(tile it+1)
// -> 16 MFMA/wave -> barrier -> ds_write regs(buf nxt). The vmcnt wait for the
// prefetch sits a full iteration after issue -> L2 latency hidden.
// LDS granule swizzle: granule p of row r stored at p^(r&3) -> ds_read/write
// both <=2-way bank aliasing (free).
// ---------------------------------------------------------------------------
__device__ __forceinline__ void gemm_kloop(const bf16* __restrict__ A,
                                           const bf16* __restrict__ BT, int m0,
                                           int n0, int tid, int wave, int lane,
                                           int m, int g, bf16* As, bf16* Bs,
                                           floatx4 (*acc)[4], int mq, int nq) {
  // staging map: granule G in [0,512): row r=G>>2, slot p=G&3; thread t owns
  // G=t and G=t+256. Source natural order; LDS dest swizzled.
  const int r0 = tid >> 2, p0 = tid & 3;
  const bf16* gA[2];
  const bf16* gB[2];
  int ldsoff[2];
#pragma unroll
  for (int h = 0; h < 2; h++) {
    const int r = r0 + 64 * h;
    gA[h] = &A[(size_t)(m0 + r) * 1024 + 8 * p0];
    gB[h] = &BT[(size_t)(n0 + r) * 1024 + 8 * p0];
    ldsoff[h] = r * 32 + 8 * (p0 ^ (r & 3));
  }

  bf16x8 ra[2], rb[2];
  // prologue: tile 0 -> buf 0
#pragma unroll
  for (int h = 0; h < 2; h++) {
    ra[h] = *(const bf16x8*)gA[h];
    rb[h] = *(const bf16x8*)gB[h];
  }
#pragma unroll
  for (int h = 0; h < 2; h++) {
    *(bf16x8*)&As[ldsoff[h]] = ra[h];
    *(bf16x8*)&Bs[ldsoff[h]] = rb[h];
  }

  for (int it = 0; it < 32; ++it) {
    const int cur = it & 1, nxt = cur ^ 1;
    __syncthreads();  // buf[cur] writes visible to all waves
    // ---- issue prefetch for tile it+1 (resolved at ds_write below) ----
    if (it + 1 < 32) {
      const int k0 = (it + 1) * 32;
#pragma unroll
      for (int h = 0; h < 2; h++) {
        ra[h] = *(const bf16x8*)(gA[h] + k0);
        rb[h] = *(const bf16x8*)(gB[h] + k0);
      }
    }
    // ---- fragments from current buffer ----
    const bf16* Ac = As + cur * (128 * 32);
    const bf16* Bcur = Bs + cur * (128 * 32);
    bf16x8 bb[4];
#pragma unroll
    for (int j = 0; j < 4; j++) {
      const int row = nq + 16 * j + m;
      bb[j] = *(const bf16x8*)&Bcur[row * 32 + 8 * (g ^ (row & 3))];
    }
#pragma unroll
    for (int i = 0; i < 4; i++) {
      const int row = mq + 16 * i + m;
      const bf16x8 a0 = *(const bf16x8*)&Ac[row * 32 + 8 * (g ^ (row & 3))];
#pragma unroll
      for (int j = 0; j < 4; j++) acc[i][j] = MFMA16(a0, bb[j], acc[i][j]);
    }
    // ---- stage prefetched tile into the other buffer ----
    if (it + 1 < 32) {
      __syncthreads();  // all waves done reading buf[nxt] (iter it-1)
      bf16* An = As + nxt * (128 * 32);
      bf16* Bn = Bs + nxt * (128 * 32);
#pragma unroll
      for (int h = 0; h < 2; h++) {
        *(bf16x8*)&An[ldsoff[h]] = ra[h];
        *(bf16x8*)&Bn[ldsoff[h]] = rb[h];
      }
    }
  }
}

// ---------------------------------------------------------------------------
// Fused Q-proj + KV-proj. grid (64, 9): y<8 -> Q tiles (RoPE+QSCALE -> qh),
// y==8 -> KV tile (RoPE -> kk / transpose -> vt).
// ---------------------------------------------------------------------------
__global__ __launch_bounds__(256, 3) void gemm_qkv(
    const bf16* __restrict__ qA, const bf16* __restrict__ qBT,
    const float* __restrict__ qb, const bf16* __restrict__ kvA,
    const bf16* __restrict__ kvBT, const float* __restrict__ kvb,
    bf16* __restrict__ qh, bf16* __restrict__ kko, bf16* __restrict__ vto) {
  __shared__ bf16 As[2 * 128 * 32];
  __shared__ bf16 Bs[2 * 128 * 32];

  const int tid = threadIdx.x, lane = tid & 63, wave = tid >> 6;
  const int m = lane & 15, g = lane >> 4;
  const int m0 = blockIdx.x * 128;
  const bool isQ = (blockIdx.y < 8);
  const int n0 = isQ ? blockIdx.y * 128 : 0;
  const bf16* A = isQ ? qA : kvA;
  const bf16* BT = isQ ? qBT : kvBT;
  const float* bias = isQ ? qb : kvb;
  const int mq = (wave >> 1) * 64, nq = (wave & 1) * 64;

  floatx4 z = {0.f, 0.f, 0.f, 0.f};
  floatx4 acc[4][4];
#pragma unroll
  for (int i = 0; i < 4; i++)
#pragma unroll
    for (int j = 0; j < 4; j++) acc[i][j] = z;

  gemm_kloop(A, BT, m0, n0, tid, wave, lane, m, g, As, Bs, acc, mq, nq);

  const int rq = 4 * g;
#pragma unroll
  for (int j = 0; j < 4; j++) {
    const int col = n0 + nq + 16 * j + m;
    const float bv = bias[col];
#pragma unroll
    for (int i = 0; i < 4; i++) {
#pragma unroll
      for (int r = 0; r < 4; r++) {
        const int row = m0 + mq + 16 * i + rq + r;
        float v = acc[i][j][r] + bv;
        const float vp = __shfl_xor(v, 1);
        if (isQ) {
          const int d = col & 63, hh = col >> 6;
          const int pos = row & (SQc - 1), b = row >> 11;
          const float ang = (float)pos * exp2f(-0.375f * (float)(d >> 1));
          float sn, cs;
          sincosf(ang, &sn, &cs);
          const float res = (d & 1) ? (v * cs + vp * sn) : (v * cs - vp * sn);
          qh[(((size_t)(b * Hc + hh) * SQc) + pos) * Dc + d] = (bf16)(res * QSCALE);
        } else {
          const int pos = row & (SKVc - 1), b = row >> 11;
          if (col < 64) {  // wave-uniform (nq is 0 or 64)
            const int d = col;
            const float ang = (float)pos * exp2f(-0.375f * (float)(d >> 1));
            float sn, cs;
            sincosf(ang, &sn, &cs);
            const float res = (d & 1) ? (v * cs + vp * sn) : (v * cs - vp * sn);
            kko[((size_t)b * SKVc + pos) * Dc + d] = (bf16)res;
          } else {
            vto[((size_t)b * Dc + (col - 64)) * SKVc + pos] = (bf16)v;
          }
        }
      }
    }
  }
}

// ---------------------------------------------------------------------------
// O-projection: fp32 out. grid (64, 8).
// ---------------------------------------------------------------------------
__global__ __launch_bounds__(256, 3) void gemm_out(
    const bf16* __restrict__ A, const bf16* __restrict__ BT,
    const float* __restrict__ bias, float* __restrict__ out) {
  __shared__ bf16 As[2 * 128 * 32];
  __shared__ bf16 Bs[2 * 128 * 32];

  const int tid = threadIdx.x, lane = tid & 63, wave = tid >> 6;
  const int m = lane & 15, g = lane >> 4;
  const int m0 = blockIdx.x * 128, n0 = blockIdx.y * 128;
  const int mq = (wave >> 1) * 64, nq = (wave & 1) * 64;

  floatx4 z = {0.f, 0.f, 0.f, 0.f};
  floatx4 acc[4][4];
#pragma unroll
  for (int i = 0; i < 4; i++)
#pragma unroll
    for (int j = 0; j < 4; j++) acc[i][j] = z;

  gemm_kloop(A, BT, m0, n0, tid, wave, lane, m, g, As, Bs, acc, mq, nq);

  const int rq = 4 * g;
#pragma unroll
  for (int j = 0; j < 4; j++) {
    const int col = n0 + nq + 16 * j + m;
    const float bv = bias[col];
#pragma unroll
    for (int i = 0; i < 4; i++)
#pragma unroll
      for (int r = 0; r < 4; r++) {
        const int row = m0 + mq + 16 * i + rq + r;
        out[(size_t)row * 1024 + col] = acc[i][j][r] + bv;
      }
  }
}

// ---------------------------------------------------------------------------
// Flash attention v5: barrier-free, 64 q-rows per wave (4 s-blocks of 16).
// P relayout buffers PRIVATE per s-block -> no LDS aliasing between s-blocks,
// so the 4 chains (QK -> exp2 -> ds_write | ds_read -> PV) pipeline freely.
// K prefetched one iter ahead in registers; V loaded at iter top. Row-sums
// via MFMA against ones. Block = 256 q-rows. Grid = 512.
// ---------------------------------------------------------------------------
__global__ __launch_bounds__(256, 2) void attn_v5(
    const bf16* __restrict__ qh, const bf16* __restrict__ kk,
    const bf16* __restrict__ vt, bf16* __restrict__ hout) {
  const int bid = blockIdx.x;
  const int qt = bid & 7, h = (bid >> 3) & 15, b = bid >> 7;
  const int tid = threadIdx.x, lane = tid & 63, wave = tid >> 6;
  const int m = lane & 15, g = lane >> 4;

  __shared__ bf16 Pb[4][4][16][68];  // [wave][s-block][q][key] - private per s

  const int q0 = qt * 256 + wave * 64;
  // Q fragments (B-operand: n=q in lane&15, k=d)
  const bf16* qp = qh + (((size_t)(b * Hc + h) * SQc) + q0 + m) * Dc + 8 * g;
  bf16x8 bq[4][2];
#pragma unroll
  for (int s = 0; s < 4; s++) {
    bq[s][0] = *(const bf16x8*)(qp + (size_t)(16 * s) * Dc);
    bq[s][1] = *(const bf16x8*)(qp + (size_t)(16 * s) * Dc + 32);
  }

  const bf16 one = (bf16)1.0f;
  const bf16x8 ones = {one, one, one, one, one, one, one, one};

  floatx4 z = {0.f, 0.f, 0.f, 0.f};
  floatx4 accO[4][4];
  floatx4 lacc[4] = {z, z, z, z};
#pragma unroll
  for (int s = 0; s < 4; s++)
#pragma unroll
    for (int t = 0; t < 4; t++) accO[s][t] = z;

  const bf16* kb = kk + (size_t)b * SKVc * Dc;
  const bf16* vb = vt + ((size_t)b * Dc + m) * SKVc + 8 * g;

  // preload K fragments for iteration 0
  bf16x8 kf[4][2];
#pragma unroll
  for (int c = 0; c < 4; c++) {
    const bf16* kp = kb + (size_t)(16 * c + m) * Dc + 8 * g;
    kf[c][0] = *(const bf16x8*)kp;
    kf[c][1] = *(const bf16x8*)(kp + 32);
  }

  for (int it = 0; it < 32; ++it) {
    const int kt = it * 64;
    // ---- V loads for current iter (consumed in phase 2) ----
    bf16x8 vf[4][2];
#pragma unroll
    for (int t = 0; t < 4; t++) {
      const bf16* vp = vb + (size_t)(16 * t) * SKVc + kt;
      vf[t][0] = *(const bf16x8*)vp;
      vf[t][1] = *(const bf16x8*)(vp + 32);
    }
    // ---- K prefetch for next iter ----
    bf16x8 kn[4][2];
    if (it + 1 < 32) {
#pragma unroll
      for (int c = 0; c < 4; c++) {
        const bf16* kp = kb + (size_t)(kt + 64 + 16 * c + m) * Dc + 8 * g;
        kn[c][0] = *(const bf16x8*)kp;
        kn[c][1] = *(const bf16x8*)(kp + 32);
      }
    }
    // ---- phase 1: all s-blocks QK + exp2 + ds_write (independent buffers) --
#pragma unroll
    for (int s = 0; s < 4; s++) {
#pragma unroll
      for (int c = 0; c < 4; c++) {
        floatx4 sv = MFMA16(kf[c][0], bq[s][0], z);
        sv = MFMA16(kf[c][1], bq[s][1], sv);
        bf16x4 pk = {(bf16)EXP2F(sv[0]), (bf16)EXP2F(sv[1]), (bf16)EXP2F(sv[2]),
                     (bf16)EXP2F(sv[3])};
        *(bf16x4*)&Pb[wave][s][m][16 * c + 4 * g] = pk;
      }
    }
    // ---- phase 2: per s-block read P (A-layout) and accumulate PV ----
#pragma unroll
    for (int s = 0; s < 4; s++) {
      const bf16x8 pa0 = *(const bf16x8*)&Pb[wave][s][m][8 * g];
      const bf16x8 pa1 = *(const bf16x8*)&Pb[wave][s][m][32 + 8 * g];
      lacc[s] = MFMA16(pa0, ones, lacc[s]);
      lacc[s] = MFMA16(pa1, ones, lacc[s]);
#pragma unroll
      for (int t = 0; t < 4; t++) {
        accO[s][t] = MFMA16(pa0, vf[t][0], accO[s][t]);
        accO[s][t] = MFMA16(pa1, vf[t][1], accO[s][t]);
      }
    }
#pragma unroll
    for (int c = 0; c < 4; c++) {
      kf[c][0] = kn[c][0];
      kf[c][1] = kn[c][1];
    }
  }

  // ---- normalize and store h[b][s][h*64+d] ----
#pragma unroll
  for (int s = 0; s < 4; s++) {
    floatx4 inv;
#pragma unroll
    for (int r = 0; r < 4; r++) inv[r] = 1.0f / lacc[s][r];
#pragma unroll
    for (int t = 0; t < 4; t++)
#pragma unroll
      for (int r = 0; r < 4; r++) {
        const int qrow = q0 + 16 * s + 4 * g + r;
        hout[((size_t)(b * SQc + qrow)) * (Hc * Dc) + h * Dc + 16 * t + m] =
            (bf16)(accO[s][t][r] * inv[r]);
      }
  }
}

// ---------------------------------------------------------------------------
extern "C" void kernel_launch(void* const* d_in, const int* in_sizes, int n_in,
                              void* d_out, int out_size, void* d_ws, size_t ws_size,
                              hipStream_t stream) {
  const float* q = (const float*)d_in[0];
  const float* kv = (const float*)d_in[1];
  const float* Wq = (const float*)d_in[2];
  const float* bq = (const float*)d_in[3];
  const float* Wkv = (const float*)d_in[4];
  const float* bkv = (const float*)d_in[5];
  const float* Wo = (const float*)d_in[6];
  const float* bo = (const float*)d_in[7];

  char* ws = (char*)d_ws;
  bf16* qbf = (bf16*)ws;                            // 16 MiB (reused as hh later)
  bf16* kvbf = (bf16*)(ws + ((size_t)16 << 20));    // 16 MiB
  bf16* WqT = (bf16*)(ws + ((size_t)32 << 20));     // 2 MiB
  bf16* WkvT = (bf16*)(ws + ((size_t)34 << 20));    // 256 KiB
  bf16* WoT = (bf16*)(ws + ((size_t)35 << 20));     // 2 MiB
  bf16* qh = (bf16*)(ws + ((size_t)37 << 20));      // 16 MiB
  bf16* kk = (bf16*)(ws + ((size_t)53 << 20));      // 1 MiB
  bf16* vt = (bf16*)(ws + ((size_t)54 << 20));      // 1 MiB
  bf16* hh = qbf;  // alias: qbf dead after gemm_qkv, hh written by attn

  const int M = Bc * SQc;  // 8192

  cvt_bf16<<<M, 256, 0, stream>>>(q, qbf);
  cvt_bf16<<<M, 256, 0, stream>>>(kv, kvbf);
  transpose_cvt<<<dim3(16, 16), 256, 0, stream>>>(Wq, WqT, 1024, 1024);
  transpose_cvt<<<dim3(2, 16), 256, 0, stream>>>(Wkv, WkvT, 1024, 128);
  transpose_cvt<<<dim3(16, 16), 256, 0, stream>>>(Wo, WoT, 1024, 1024);

  gemm_qkv<<<dim3(64, 9), 256, 0, stream>>>(qbf, WqT, bq, kvbf, WkvT, bkv, qh, kk,
                                            vt);
  attn_v5<<<Bc * Hc * (SQc / 256), 256, 0, stream>>>(qh, kk, vt, hh);
  gemm_out<<<dim3(64, 8), 256, 0, stream>>>(hh, WoT, bo, (float*)d_out);
}